// Round 3
// baseline (307.673 us; speedup 1.0000x reference)
//
#include <hip/hip_runtime.h>
#include <stdint.h>

#define N_ROWS 8192
#define IN_F   1024
#define OUT_F  1024
#define NG     5
#define KTOT   (IN_F * NG)  // 5120, k = g*1024 + i (g-major)

#define BM 128
#define BN 128
#define BK 64
#define NKT (KTOT / BK)     // 80

typedef float          f32x4 __attribute__((ext_vector_type(4)));
typedef short          s16x8 __attribute__((ext_vector_type(8)));
typedef unsigned short u16x8 __attribute__((ext_vector_type(8)));

__device__ __forceinline__ unsigned short f2bf_rne(float f) {
    unsigned u = __float_as_uint(f);
    u = (u + 0x7fffu + ((u >> 16) & 1u)) >> 16;
    return (unsigned short)u;
}
__device__ __forceinline__ float bf2f(unsigned short h) {
    return __uint_as_float(((unsigned)h) << 16);
}

// async global->LDS, 16B/lane; LDS dest = wave-uniform base + lane*16
// (swizzle lives in the per-lane GLOBAL address — m173 pattern, rule #21)
__device__ __forceinline__ void gload_lds16(const void* g, void* l) {
    __builtin_amdgcn_global_load_lds(
        (const __attribute__((address_space(1))) unsigned int*)g,
        (__attribute__((address_space(3))) unsigned int*)l, 16, 0, 0);
}

// ---------- prep 1: P[n][i] = u16 encode of tanh(x[n][i]) ----------
// u = rint((tanh+1)*32767); decode xc = u/32767-1 (max err 1.5e-5; hat-basis
// continuity -> ~2e-5 rel on outputs). Fast tanh via exp; clamp avoids NaN.
__global__ __launch_bounds__(256) void prep_p(const float* __restrict__ x,
                                              unsigned short* __restrict__ P) {
    int t = blockIdx.x * 256 + threadIdx.x;        // x 4 elems
    float4 v = reinterpret_cast<const float4*>(x)[t];
    float r[4] = {v.x, v.y, v.z, v.w};
    ushort4 o;
    unsigned short* po = (unsigned short*)&o;
#pragma unroll
    for (int j = 0; j < 4; ++j) {
        float xc = fminf(fmaxf(r[j], -9.0f), 9.0f);
        float e  = __expf(2.0f * xc);
        float th = (e - 1.0f) / (e + 1.0f);
        po[j] = (unsigned short)__float2uint_rn((th + 1.0f) * 32767.0f);
    }
    reinterpret_cast<ushort4*>(P)[t] = o;
}

// ---------- prep 2: split W[o][i][g] fp32 -> Wh/Wl bf16 planes [o][g*1024+i] ----------
__global__ __launch_bounds__(256) void prep_w(const float* __restrict__ W,
                                              unsigned short* __restrict__ Wh,
                                              unsigned short* __restrict__ Wl) {
    int t = blockIdx.x * 256 + threadIdx.x;        // (o,i)
    int o = t >> 10, i = t & 1023;
    const float* wp = W + (size_t)o * KTOT + i * NG;
#pragma unroll
    for (int g = 0; g < NG; ++g) {
        float w = wp[g];
        unsigned short h = f2bf_rne(w);
        unsigned short l = f2bf_rne(w - bf2f(h));   // residual, rel ~2^-18
        int dst = o * KTOT + g * 1024 + i;          // coalesced along i per g
        Wh[dst] = h;
        Wl[dst] = l;
    }
}

// ---------- main: out[8192,1024] = C x W^T via 3-product split-bf16 MFMA ----------
// LDS layout (all 4 planes): elem[row*64 + sw*8 + j] = T[row][(sw^(row&7))*8 + j]
// read-side: 16 lanes hit 16 consecutive rows at one k-chunk -> 8 slots x 4
// banks = all 32 banks, only the free 2-way wave64 aliasing (m136).
struct SLds {
    unsigned short Ah[BM * BK];
    unsigned short Al[BM * BK];
    unsigned short Bh[BN * BK];
    unsigned short Bl[BN * BK];
};                                                  // 65536 B

__global__ __launch_bounds__(256, 2) void kan_gemm(
        const unsigned short* __restrict__ P,
        const unsigned short* __restrict__ Wh,
        const unsigned short* __restrict__ Wl,
        float* __restrict__ out) {
    __shared__ SLds s;

    // bijective XCD swizzle: 512 = 8 XCDs x 64; XCD x owns o-panel x
    // (B-panel 128 x 5120 x 2 planes x 2B = 2.6 MB -> L2-resident)
    int bid = blockIdx.x;
    int wg  = (bid & 7) * 64 + (bid >> 3);
    int nb  = wg >> 6;                  // 0..7   o-panel
    int mb  = wg & 63;                  // 0..63  n-panel
    int n0 = mb * BM, o0 = nb * BN;

    int tid  = threadIdx.x;
    int lane = tid & 63, wid = tid >> 6;
    int wm = wid >> 1, wn = wid & 1;    // wave grid 2x2, wave-tile 64x64

    // ---- hoisted per-lane addressing ----
    int aoff[4], adst[4];
#pragma unroll
    for (int r = 0; r < 4; ++r) {
        int f = tid + r * 256, row = f >> 3, ks = f & 7;
        aoff[r] = (n0 + row) * IN_F + ks * 8;                 // + i0 per kt
        adst[r] = row * BK + ((ks ^ (row & 7)) << 3);
    }
    // B gload_lds: lane l -> chunk row l>>3, LDS slot l&7; global ks undoes
    // the read-side XOR: ks = (l&7) ^ (l>>3)  (row&7 == l>>3 here)
    int bks = (lane & 7) ^ (lane >> 3);
    int boff[4];
#pragma unroll
    for (int q = 0; q < 4; ++q)
        boff[q] = (o0 + wid * 32 + q * 8 + (lane >> 3)) * KTOT + bks * 8; // + k0
    int arow_f = wm * 64 + (lane & 15);   // + m*16
    int brow_f = wn * 64 + (lane & 15);   // + nf*16
    int sl0    = lane >> 4;               // k-chunk base; + kk*4, then ^(row&7)

    f32x4 acc[4][4] = {};

    // ---- T14 pipeline: P-regs for tile kt prefetched during tile kt-1 ----
    u16x8 ucur[4], unext[4];
#pragma unroll
    for (int r = 0; r < 4; ++r)
        ucur[r] = *reinterpret_cast<const u16x8*>(&P[aoff[r]]);  // kt=0: i0=0

    for (int kt = 0; kt < NKT; ++kt) {
        int k0 = kt * BK;
        int g  = k0 >> 10;              // whole tile shares one g (g-major k)
        float gv = -1.0f + 0.5f * (float)g;
        int i0n = ((kt + 1 < NKT) ? (kt + 1) * BK : 0) & 1023; // next tile's i0

        __syncthreads();                // barrier-1: prev tile's LDS reads done

        // ---- B: issue async gl_lds; latency hides under A's VALU below ----
#pragma unroll
        for (int q = 0; q < 4; ++q) {
            int ldsrow = (wid * 32 + q * 8) * BK;
            gload_lds16(Wh + boff[q] + k0, &s.Bh[ldsrow]);
            gload_lds16(Wl + boff[q] + k0, &s.Bl[ldsrow]);
        }
        // ---- issue next tile's P loads now (use-late; hides L2/HBM lat) ----
#pragma unroll
        for (int r = 0; r < 4; ++r)
            unext[r] = *reinterpret_cast<const u16x8*>(&P[aoff[r] + i0n]);

        // ---- A: hat-basis coeffs c = max(0, 1-2|xc-gv|) from ucur;
        //      split trunc-hi / trunc-lo (AlBl-class err ~2^-17 rel) ----
#pragma unroll
        for (int r = 0; r < 4; ++r) {
            u16x8 hv, lv;
#pragma unroll
            for (int j = 0; j < 8; ++j) {
                float xc = fmaf((float)ucur[r][j], (1.0f / 32767.0f), -1.0f);
                float c  = fmaxf(0.0f, fmaf(-2.0f, fabsf(xc - gv), 1.0f));
                unsigned hb = __float_as_uint(c) >> 16;         // trunc (c>=0)
                hv[j] = (unsigned short)hb;
                float hi = __uint_as_float(hb << 16);
                lv[j] = (unsigned short)(__float_as_uint(c - hi) >> 16);
            }
            *reinterpret_cast<u16x8*>(&s.Ah[adst[r]]) = hv;
            *reinterpret_cast<u16x8*>(&s.Al[adst[r]]) = lv;
        }
#pragma unroll
        for (int r = 0; r < 4; ++r) ucur[r] = unext[r];

        __syncthreads();                // vmcnt(0) drain: B + P-prefetch landed

        // ---- compute: AhBh + AhBl + AlBh ----
#pragma unroll
        for (int kk = 0; kk < 2; ++kk) {
            s16x8 ah[4], al[4], bh[4], bl[4];
#pragma unroll
            for (int m = 0; m < 4; ++m) {
                int row  = arow_f + m * 16;
                int slot = (kk * 4 + sl0) ^ (row & 7);
                ah[m] = *reinterpret_cast<const s16x8*>(&s.Ah[row * BK + slot * 8]);
                al[m] = *reinterpret_cast<const s16x8*>(&s.Al[row * BK + slot * 8]);
            }
#pragma unroll
            for (int nf = 0; nf < 4; ++nf) {
                int row  = brow_f + nf * 16;
                int slot = (kk * 4 + sl0) ^ (row & 7);
                bh[nf] = *reinterpret_cast<const s16x8*>(&s.Bh[row * BK + slot * 8]);
                bl[nf] = *reinterpret_cast<const s16x8*>(&s.Bl[row * BK + slot * 8]);
            }
#pragma unroll
            for (int m = 0; m < 4; ++m)
#pragma unroll
                for (int nf = 0; nf < 4; ++nf) {
                    acc[m][nf] = __builtin_amdgcn_mfma_f32_16x16x32_bf16(
                                     ah[m], bh[nf], acc[m][nf], 0, 0, 0);
                    acc[m][nf] = __builtin_amdgcn_mfma_f32_16x16x32_bf16(
                                     ah[m], bl[nf], acc[m][nf], 0, 0, 0);
                    acc[m][nf] = __builtin_amdgcn_mfma_f32_16x16x32_bf16(
                                     al[m], bh[nf], acc[m][nf], 0, 0, 0);
                }
        }
    }

    // ---- epilogue: C/D layout col=lane&15, row=(lane>>4)*4+reg (m89/m91) ----
    int rb = n0 + wm * 64 + (lane >> 4) * 4;
    int cb = o0 + wn * 64 + (lane & 15);
#pragma unroll
    for (int m = 0; m < 4; ++m)
#pragma unroll
        for (int nf = 0; nf < 4; ++nf)
#pragma unroll
            for (int jj = 0; jj < 4; ++jj)
                out[(size_t)(rb + m * 16 + jj) * OUT_F + cb + nf * 16] =
                    acc[m][nf][jj];
}

// ---------- fallback (only if ws too small): correct, slow ----------
__global__ __launch_bounds__(256) void kan_naive(const float* __restrict__ x,
                                                 const float* __restrict__ W,
                                                 float* __restrict__ out) {
    int bn = blockIdx.x & 3;
    int bm = blockIdx.x >> 2;
    int o = bn * 256 + threadIdx.x;
    int nbase = bm * 16;
    float acc[16];
#pragma unroll
    for (int j = 0; j < 16; ++j) acc[j] = 0.0f;
    for (int i = 0; i < IN_F; ++i) {
        const float* wp = &W[(size_t)o * KTOT + i * NG];
        float w0 = wp[0], w1 = wp[1], w2 = wp[2], w3 = wp[3], w4 = wp[4];
#pragma unroll
        for (int j = 0; j < 16; ++j) {
            float xc = tanhf(x[(size_t)(nbase + j) * IN_F + i]);
            float c0 = fmaxf(0.f, fmaf(-2.f, fabsf(xc + 1.0f), 1.f));
            float c1 = fmaxf(0.f, fmaf(-2.f, fabsf(xc + 0.5f), 1.f));
            float c2 = fmaxf(0.f, fmaf(-2.f, fabsf(xc), 1.f));
            float c3 = fmaxf(0.f, fmaf(-2.f, fabsf(xc - 0.5f), 1.f));
            float c4 = fmaxf(0.f, fmaf(-2.f, fabsf(xc - 1.0f), 1.f));
            acc[j] += c0 * w0 + c1 * w1 + c2 * w2 + c3 * w3 + c4 * w4;
        }
    }
#pragma unroll
    for (int j = 0; j < 16; ++j)
        out[(size_t)(nbase + j) * OUT_F + o] = acc[j];
}

extern "C" void kernel_launch(void* const* d_in, const int* in_sizes, int n_in,
                              void* d_out, int out_size, void* d_ws, size_t ws_size,
                              hipStream_t stream) {
    const float* x = (const float*)d_in[0];
    const float* W = (const float*)d_in[1];
    float* out = (float*)d_out;

    const size_t P_BYTES = (size_t)N_ROWS * IN_F * 2;      // 16 MiB
    const size_t WPLANE  = (size_t)OUT_F * KTOT * 2;       // 10 MiB each

    if (ws_size >= P_BYTES + 2 * WPLANE) {
        unsigned short* P  = (unsigned short*)d_ws;
        unsigned short* Wh = (unsigned short*)((char*)d_ws + P_BYTES);
        unsigned short* Wl = (unsigned short*)((char*)d_ws + P_BYTES + WPLANE);
        prep_p<<<(N_ROWS * IN_F / 4) / 256, 256, 0, stream>>>(x, P);
        prep_w<<<(OUT_F * IN_F) / 256, 256, 0, stream>>>(W, Wh, Wl);
        kan_gemm<<<512, 256, 0, stream>>>(P, Wh, Wl, out);
    } else {
        kan_naive<<<2048, 256, 0, stream>>>(x, W, out);
    }
}